// Round 10
// baseline (260.992 us; speedup 1.0000x reference)
//
#include <hip/hip_runtime.h>

typedef float f32x4 __attribute__((ext_vector_type(4)));
typedef short s16x8 __attribute__((ext_vector_type(8)));

#define NB_    32
#define NLC    2048
#define NLT    512
#define ND     256
#define NCHUNK 512
#define NITER  (NCHUNK / 32)

__device__ __forceinline__ unsigned short f2bf(float f) {
    union { float f; unsigned int u; } v; v.f = f;
    unsigned int r = v.u + 0x7FFFu + ((v.u >> 16) & 1u);   // RNE to bf16
    return (unsigned short)(r >> 16);
}

__device__ __forceinline__ s16x8 cvt8(float4 a, float4 c, float s) {
    s16x8 f;
    f[0]=(short)f2bf(s*a.x); f[1]=(short)f2bf(s*a.y); f[2]=(short)f2bf(s*a.z); f[3]=(short)f2bf(s*a.w);
    f[4]=(short)f2bf(s*c.x); f[5]=(short)f2bf(s*c.y); f[6]=(short)f2bf(s*c.z); f[7]=(short)f2bf(s*c.w);
    return f;
}

// async global->LDS, 16B per lane (dest = wave-uniform base + lane*16)
__device__ __forceinline__ void glds16(const void* g, void* l) {
    __builtin_amdgcn_global_load_lds(
        (const __attribute__((address_space(1))) unsigned int*)g,
        (__attribute__((address_space(3))) unsigned int*)l, 16, 0, 0);
}

// ---------------------------------------------------------------------------
// Prep: bf16 copies of ctx/tgt + row squared-norms. One wave per row.
// ---------------------------------------------------------------------------
__global__ __launch_bounds__(256) void prep_kernel(
    const float* __restrict__ ctx, const float* __restrict__ tgt,
    float* __restrict__ norms,
    unsigned short* __restrict__ ctxb, unsigned short* __restrict__ tgtb)
{
    const int wave = threadIdx.x >> 6;
    const int lane = threadIdx.x & 63;
    const int rid = blockIdx.x * 4 + wave;
    const float* row;
    unsigned short* drow;
    if (rid < NB_ * NLC) { row = ctx + (size_t)rid * ND; drow = ctxb + (size_t)rid * ND; }
    else { row = tgt + (size_t)(rid - NB_ * NLC) * ND; drow = tgtb + (size_t)(rid - NB_ * NLC) * ND; }
    const float4 v = *(const float4*)(row + lane * 4);
    *(ushort4*)(drow + lane * 4) = make_ushort4(f2bf(v.x), f2bf(v.y), f2bf(v.z), f2bf(v.w));
    float s = v.x * v.x + v.y * v.y + v.z * v.z + v.w * v.w;
    #pragma unroll
    for (int off = 32; off >= 1; off >>= 1) s += __shfl_xor(s, off);
    if (lane == 0) norms[rid] = s;
}

// ---------------------------------------------------------------------------
// Transpose bf16 copies: per batch, [L][256] -> [256][L]. 64x64 tiles via LDS.
// ---------------------------------------------------------------------------
__global__ __launch_bounds__(256) void transpose_bf(
    const unsigned short* __restrict__ ctxb, const unsigned short* __restrict__ tgtb,
    unsigned short* __restrict__ ctxT, unsigned short* __restrict__ tgtT)
{
    __shared__ unsigned short tile[64][72];
    const int id = blockIdx.x;
    const unsigned short* in;
    unsigned short* outp;
    int ldL;
    if (id < 4096) {
        const int b = id >> 7, r = id & 127, lt = r >> 2, dt = r & 3;
        in   = ctxb + ((size_t)b * NLC + lt * 64) * ND + dt * 64;
        outp = ctxT + ((size_t)b * ND + dt * 64) * NLC + lt * 64;
        ldL = NLC;
    } else {
        const int id2 = id - 4096;
        const int b = id2 >> 5, r = id2 & 31, lt = r >> 2, dt = r & 3;
        in   = tgtb + ((size_t)b * NLT + lt * 64) * ND + dt * 64;
        outp = tgtT + ((size_t)b * ND + dt * 64) * NLT + lt * 64;
        ldL = NLT;
    }
    const int t = threadIdx.x;
    const int r0 = t >> 2, c0 = t & 3;
    const s16x8 v0 = *(const s16x8*)&in[(size_t)r0 * ND + c0 * 8];
    const s16x8 v1 = *(const s16x8*)&in[(size_t)r0 * ND + (c0 + 4) * 8];
    *(s16x8*)&tile[r0][c0 * 8] = v0;
    *(s16x8*)&tile[r0][(c0 + 4) * 8] = v1;
    __syncthreads();
    unsigned short buf[16];
    #pragma unroll
    for (int i = 0; i < 16; ++i) buf[i] = tile[(t & 3) * 16 + i][t >> 2];
    unsigned short* op = outp + (size_t)(t >> 2) * ldL + (t & 3) * 16;
    *(s16x8*)&op[0] = *(const s16x8*)&buf[0];
    *(s16x8*)&op[8] = *(const s16x8*)&buf[8];
}

// ---------------------------------------------------------------------------
// K1: S = ctx.tgt^T -> weights, written in PACKED panel layouts:
//   Wp [b][ts=t/64][c 2048][64]   (k2's B: per-k-step panels contiguous)
//   WTp[b][cs=c/64][t  512][64]   (k3's B: per-k-step panels contiguous)
// ---------------------------------------------------------------------------
__global__ __launch_bounds__(256, 2) void k1_weights(
    const unsigned short* __restrict__ ctxb, const unsigned short* __restrict__ tgtb,
    const float* __restrict__ norms,
    unsigned short* __restrict__ Wg, unsigned short* __restrict__ WTg)
{
    __shared__ __align__(16) unsigned short Alds[2][128 * 64];   // [c][k] swz; reused as WTs
    __shared__ __align__(16) unsigned short Blds[2][128 * 64];   // [t][k] swz
    __shared__ __align__(16) unsigned short relay[4][16 * 128];

    const int phys = blockIdx.x;
    const int L = (phys & 7) * 256 + (phys >> 3);   // grid 2048, bijective
    const int b = L >> 6;
    const int r = L & 63;
    const int cb = r >> 2, tb = r & 3;

    const int tid = threadIdx.x, wave = tid >> 6, lane = tid & 63;
    const int lr = lane & 15, lq = lane >> 4;
    const int cw = cb * 128 + wave * 32;

    const unsigned short* Actx = ctxb + ((size_t)b * NLC + cb * 128) * ND;
    const unsigned short* Btgt = tgtb + ((size_t)b * NLT + tb * 128) * ND;

    auto STAGE = [&](int buf, int ks) {
        #pragma unroll
        for (int i = 0; i < 4; ++i) {
            const int q = wave * 4 + i;
            const int rloc = q * 8 + (lane >> 3);
            const int gcol = (lane & 7) ^ (rloc & 7);
            glds16(Actx + (size_t)rloc * ND + ks * 64 + gcol * 8, &Alds[buf][q * 512]);
            glds16(Btgt + (size_t)rloc * ND + ks * 64 + gcol * 8, &Blds[buf][q * 512]);
        }
    };

    f32x4 acc[2][8];
    #pragma unroll
    for (int mf = 0; mf < 2; ++mf)
        #pragma unroll
        for (int nf = 0; nf < 8; ++nf) acc[mf][nf] = (f32x4)(0.0f);

    STAGE(0, 0);
    int buf = 0;
    for (int ks = 0; ks < 4; ++ks) {
        __syncthreads();
        if (ks < 3) STAGE(buf ^ 1, ks + 1);
        #pragma unroll
        for (int kk = 0; kk < 2; ++kk) {
            s16x8 af[2];
            #pragma unroll
            for (int mf = 0; mf < 2; ++mf) {
                const int row = wave * 32 + mf * 16 + lr;
                af[mf] = *(const s16x8*)&Alds[buf][row * 64 + (((kk * 4 + lq) ^ (row & 7)) * 8)];
            }
            #pragma unroll
            for (int nf = 0; nf < 8; ++nf) {
                const int row = nf * 16 + lr;
                const s16x8 bf = *(const s16x8*)&Blds[buf][row * 64 + (((kk * 4 + lq) ^ (row & 7)) * 8)];
                acc[0][nf] = __builtin_amdgcn_mfma_f32_16x16x32_bf16(af[0], bf, acc[0][nf], 0, 0, 0);
                acc[1][nf] = __builtin_amdgcn_mfma_f32_16x16x32_bf16(af[1], bf, acc[1][nf], 0, 0, 0);
            }
        }
        buf ^= 1;
    }

    float c2[2][4], t2[8];
    #pragma unroll
    for (int mf = 0; mf < 2; ++mf)
        #pragma unroll
        for (int j = 0; j < 4; ++j)
            c2[mf][j] = norms[b * NLC + cw + mf * 16 + lq * 4 + j];
    #pragma unroll
    for (int nf = 0; nf < 8; ++nf)
        t2[nf] = norms[NB_ * NLC + b * NLT + tb * 128 + nf * 16 + lr];

    __syncthreads();   // all waves done with Alds/Blds; Alds becomes WTs
    unsigned short* WTs = (unsigned short*)Alds;   // [128 t][128 c], c ^= (t&15)<<3

    #pragma unroll
    for (int mf = 0; mf < 2; ++mf) {
        #pragma unroll
        for (int nf = 0; nf < 8; ++nf) {
            unsigned short w4[4];
            #pragma unroll
            for (int j = 0; j < 4; ++j) {
                float d2 = c2[mf][j] + t2[nf] - 2.0f * acc[mf][nf][j];
                d2 = d2 > 0.0f ? d2 : 0.0f;
                w4[j] = f2bf(__builtin_amdgcn_rcpf(1.0f + __builtin_amdgcn_sqrtf(d2)));
                const int row = lq * 4 + j;
                relay[wave][row * 128 + ((nf * 16 + lr) ^ ((row & 7) << 3))] = w4[j];
            }
            // WT stage: t = nf*16+lr, 4 consecutive c -> vector write
            const int t = nf * 16 + lr;
            const int c4 = (wave * 32 + mf * 16 + lq * 4) ^ ((t & 15) << 3);
            *(ushort4*)&WTs[t * 128 + c4] = make_ushort4(w4[0], w4[1], w4[2], w4[3]);
        }
        __syncthreads();
        // W packed write: Wp[(b*8 + tb*2 + ts)*2048 + c][64]; lane = rrow*4 + ts*2 + half
        {
            const int rrow = lane >> 2;            // 0..15 (c within wave's 16)
            const int ts   = (lane >> 1) & 1;      // which 64-t slab
            const int half = lane & 1;             // 32-t half within slab
            const size_t wbase =
                (((size_t)b * 8 + tb * 2 + ts) * NLC + cb * 128 + wave * 32 + mf * 16 + rrow) * 64
                + half * 32;
            #pragma unroll
            for (int e = 0; e < 4; ++e) {
                const int tcol = ts * 64 + half * 32 + e * 8;
                const s16x8 v = *(const s16x8*)&relay[wave][rrow * 128 + (tcol ^ ((rrow & 7) << 3))];
                *(s16x8*)&Wg[wbase + e * 8] = v;
            }
        }
        __syncthreads();
    }

    // WT packed write: WTp[(b*32 + cb*2 + seg)*512 + t][64]; 128B contiguous/thread
    {
        const int trow = tid >> 1;           // 0..127
        const int seg  = tid & 1;            // which 64-c slab
        const size_t wtbase =
            (((size_t)b * 32 + cb * 2 + seg) * NLT + tb * 128 + trow) * 64;
        #pragma unroll
        for (int e = 0; e < 8; ++e) {
            const int c8 = (seg * 64 + e * 8) ^ ((trow & 15) << 3);
            *(s16x8*)&WTg[wtbase + e * 8] = *(const s16x8*)&WTs[trow * 128 + c8];
        }
    }
}

// ---------------------------------------------------------------------------
// K2: g2c^T GEMM, tile 128 c x 256 d, BK=64, K=512 (=t).
// A (tgtT [d][k]) staged via global_load_lds; B = Wp packed panels (contiguous).
// ---------------------------------------------------------------------------
__global__ __launch_bounds__(256, 2) void k2_gemm(
    const unsigned short* __restrict__ At, const unsigned short* __restrict__ Wp,
    float* __restrict__ outp)
{
    __shared__ __align__(16) unsigned short Slds[2][256 * 64];   // [d][k] swz

    const int phys = blockIdx.x;
    const int L = (phys & 7) * 64 + (phys >> 3);   // grid 512, bijective
    const int b = L >> 4, cb = L & 15;
    const unsigned short* Ab = At + (size_t)b * ND * NLT;
    float* outB = outp + ((size_t)b * (NLC + NLT) + cb * 128) * ND;

    const int tid = threadIdx.x, wave = tid >> 6, lane = tid & 63;
    const int lr = lane & 15, lq = lane >> 4;

    const int srow = tid >> 3;
    const int schunk = tid & 7;

    auto STAGE = [&](int buf, int ks) {
        #pragma unroll
        for (int i = 0; i < 8; ++i) {
            const int row = i * 32 + srow;
            const int gcol = schunk ^ (row & 7);
            glds16(Ab + (size_t)row * NLT + ks * 64 + gcol * 8,
                   &Slds[buf][(i * 32 + wave * 8) * 64]);
        }
    };

    f32x4 acc[16][2];
    #pragma unroll
    for (int mf = 0; mf < 16; ++mf) { acc[mf][0] = (f32x4)(0.0f); acc[mf][1] = (f32x4)(0.0f); }

    STAGE(0, 0);
    for (int ks = 0; ks < 8; ++ks) {
        __syncthreads();
        const int buf = ks & 1;
        if (ks < 7) STAGE(buf ^ 1, ks + 1);

        // B frags from packed panels: rows at 128B stride, panel contiguous
        s16x8 bfr[2][2];
        #pragma unroll
        for (int j = 0; j < 2; ++j)
            #pragma unroll
            for (int kk = 0; kk < 2; ++kk)
                bfr[j][kk] = *(const s16x8*)&Wp[
                    (((size_t)b * 8 + ks) * NLC + cb * 128 + wave * 32 + j * 16 + lr) * 64
                    + kk * 32 + lq * 8];

        __builtin_amdgcn_s_setprio(1);
        #pragma unroll
        for (int kk = 0; kk < 2; ++kk) {
            #pragma unroll
            for (int mf = 0; mf < 16; ++mf) {
                const int row = mf * 16 + lr;
                const s16x8 af = *(const s16x8*)&Slds[buf][row * 64 +
                                                           (((kk * 4 + lq) ^ (row & 7)) * 8)];
                acc[mf][0] = __builtin_amdgcn_mfma_f32_16x16x32_bf16(af, bfr[0][kk], acc[mf][0], 0, 0, 0);
                acc[mf][1] = __builtin_amdgcn_mfma_f32_16x16x32_bf16(af, bfr[1][kk], acc[mf][1], 0, 0, 0);
            }
        }
        __builtin_amdgcn_s_setprio(0);
    }

    #pragma unroll
    for (int j = 0; j < 2; ++j) {
        const int col = wave * 32 + j * 16 + lr;
        float* rp = outB + (size_t)col * ND;
        #pragma unroll
        for (int mf = 0; mf < 16; ++mf) {
            const f32x4 v = acc[mf][j];
            *(float4*)(rp + mf * 16 + lq * 4) = make_float4(v[0], v[1], v[2], v[3]);
        }
    }
}

// ---------------------------------------------------------------------------
// K3V4: g2t full-K direct from packed WT. Grid 1024 = (b, tb8 of 64t, dh of 64d).
// K = 2048 (=c), 32 k-steps. A = ctxT [64d][64k] dbuf glds; B = WTp panels
// (contiguous 2KB reads). 4 blocks/CU (16KB LDS), 16 waves/CU.
// ---------------------------------------------------------------------------
__global__ __launch_bounds__(256, 4) void k3v4(
    const unsigned short* __restrict__ ctxT, const unsigned short* __restrict__ WTp,
    float* __restrict__ out)
{
    __shared__ __align__(16) unsigned short Slds[2][64 * 64];

    const int phys = blockIdx.x;
    const int L = (phys & 7) * 128 + (phys >> 3);   // 1024, bijective
    const int b = L >> 5, r = L & 31;
    const int tb8 = r >> 2, dh = r & 3;

    const int tid = threadIdx.x, wave = tid >> 6, lane = tid & 63;
    const int lr = lane & 15, lq = lane >> 4;

    const unsigned short* Ab = ctxT + (size_t)b * ND * NLC + (size_t)(dh * 64) * NLC;

    auto STAGE = [&](int buf, int ks) {
        #pragma unroll
        for (int i = 0; i < 2; ++i) {
            const int q = wave * 2 + i;
            const int rloc = q * 8 + (lane >> 3);
            const int gcol = (lane & 7) ^ (rloc & 7);
            glds16(Ab + (size_t)rloc * NLC + ks * 64 + gcol * 8, &Slds[buf][q * 512]);
        }
    };

    f32x4 acc[4];
    #pragma unroll
    for (int nf = 0; nf < 4; ++nf) acc[nf] = (f32x4)(0.0f);

    STAGE(0, 0);
    for (int ks = 0; ks < 32; ++ks) {
        __syncthreads();
        const int buf = ks & 1;
        if (ks < 31) STAGE(buf ^ 1, ks + 1);

        // B frags from packed WT panels (contiguous)
        s16x8 bfr[4][2];
        #pragma unroll
        for (int nf = 0; nf < 4; ++nf)
            #pragma unroll
            for (int kk = 0; kk < 2; ++kk)
                bfr[nf][kk] = *(const s16x8*)&WTp[
                    (((size_t)b * 32 + ks) * NLT + tb8 * 64 + nf * 16 + lr) * 64
                    + kk * 32 + lq * 8];

        __builtin_amdgcn_s_setprio(1);
        #pragma unroll
        for (int kk = 0; kk < 2; ++kk) {
            const int row = wave * 16 + lr;
            const s16x8 af = *(const s16x8*)&Slds[buf][row * 64 + (((kk * 4 + lq) ^ (row & 7)) * 8)];
            #pragma unroll
            for (int nf = 0; nf < 4; ++nf)
                acc[nf] = __builtin_amdgcn_mfma_f32_16x16x32_bf16(af, bfr[nf][kk], acc[nf], 0, 0, 0);
        }
        __builtin_amdgcn_s_setprio(0);
    }

    // epilogue: out[t][d], d = dh*64 + wave*16 + lq*4+j contiguous
    #pragma unroll
    for (int nf = 0; nf < 4; ++nf) {
        const int t = tb8 * 64 + nf * 16 + lr;
        const f32x4 v = acc[nf];
        *(float4*)(out + ((size_t)b * (NLC + NLT) + NLC + t) * ND + dh * 64 + wave * 16 + lq * 4) =
            make_float4(v[0], v[1], v[2], v[3]);
    }
}

// ===========================================================================
// R4 fused fallback (proven-correct) for small workspaces.
// ===========================================================================
__global__ __launch_bounds__(256) void zero_g2t(float* __restrict__ out) {
    const int g = blockIdx.x * 256 + threadIdx.x;
    #pragma unroll
    for (int k = 0; k < 4; ++k) {
        const int i = g + k * 262144;
        const int bb = i >> 15;
        const int off = i & 32767;
        *(float4*)(out + ((size_t)bb * (NLC + NLT) + NLC) * ND + (size_t)off * 4) =
            make_float4(0.f, 0.f, 0.f, 0.f);
    }
}

__global__ __launch_bounds__(256) void reduce_g2t(const float* __restrict__ part,
                                                  float* __restrict__ out) {
    const int g = blockIdx.x * 256 + threadIdx.x;
    #pragma unroll
    for (int k = 0; k < 4; ++k) {
        const int i = g + k * 262144;
        const int b = i >> 15;
        const int rem = i & 32767;
        const int row = rem >> 6;
        const int d4 = (rem & 63) * 4;
        const int mb = row >> 7, rr = row & 127;
        const size_t base = ((size_t)(b * 16 + mb * 4) * 32768) + (size_t)rr * 256 + d4;
        float4 s0 = *(const float4*)(part + base);
        float4 s1 = *(const float4*)(part + base + 32768);
        float4 s2 = *(const float4*)(part + base + 65536);
        float4 s3 = *(const float4*)(part + base + 98304);
        *(float4*)(out + ((size_t)b * (NLC + NLT) + NLC + row) * ND + d4) =
            make_float4(s0.x + s1.x + s2.x + s3.x, s0.y + s1.y + s2.y + s3.y,
                        s0.z + s1.z + s2.z + s3.z, s0.w + s1.w + s2.w + s3.w);
    }
}

__global__ __launch_bounds__(256, 2) void fused_dist_attn(
    const float* __restrict__ ctx, const float* __restrict__ tgt,
    float* __restrict__ out, float* __restrict__ part)
{
    __shared__ __align__(16) unsigned short Klds[2][32 * 256];
    __shared__ __align__(16) unsigned short VTlds[2][256 * 32];
    __shared__ __align__(16) unsigned short Wlds[4 * 32 * 32];
    __shared__ unsigned int KextLds[2][32];

    const int phys = blockIdx.x;
    const int L = (phys & 7) * 128 + (phys >> 3);
    const int isB = (L & 1) == 0;
    const int idx = L >> 1;
    const int b = idx >> 4;
    const float *Q, *KV;
    size_t outbase;
    if (isB) {
        const int mb = (idx >> 2) & 3, nc = idx & 3;
        Q = tgt + ((size_t)b * NLT + mb * 128) * ND;
        KV = ctx + ((size_t)b * NLC + nc * NCHUNK) * ND;
        outbase = ((size_t)b * (NLC + NLT) + NLC + mb * 128) * ND;
    } else {
        const int mb = idx & 15;
        Q = ctx + ((size_t)b * NLC + mb * 128) * ND;
        KV = tgt + (size_t)b * NLT * ND;
        outbase = ((size_t)b * (NLC + NLT) + mb * 128) * ND;
    }

    const int tid = threadIdx.x, wave = tid >> 6, lane = tid & 63;
    const int lr = lane & 15, lq = lane >> 4;

    s16x8 qf[2][8];
    s16x8 qe[2];
    #pragma unroll
    for (int mf = 0; mf < 2; ++mf) {
        const float* qrow = Q + (size_t)(wave * 32 + mf * 16 + lr) * ND;
        float q2 = 0.0f;
        #pragma unroll
        for (int kk = 0; kk < 8; ++kk) {
            const float4 a = *(const float4*)(qrow + kk * 32 + lq * 8);
            const float4 c = *(const float4*)(qrow + kk * 32 + lq * 8 + 4);
            q2 += a.x*a.x + a.y*a.y + a.z*a.z + a.w*a.w;
            q2 += c.x*c.x + c.y*c.y + c.z*c.z + c.w*c.w;
            qf[mf][kk] = cvt8(a, c, -2.0f);
        }
        q2 += __shfl_xor(q2, 16);
        q2 += __shfl_xor(q2, 32);
        union { unsigned int u[4]; s16x8 v; } qu;
        qu.u[0] = (lq == 0) ? (0x3F80u | ((unsigned int)f2bf(q2) << 16)) : 0u;
        qu.u[1] = 0u; qu.u[2] = 0u; qu.u[3] = 0u;
        qe[mf] = qu.v;
    }

    f32x4 acc[2][16];
    #pragma unroll
    for (int mf = 0; mf < 2; ++mf)
        #pragma unroll
        for (int dt = 0; dt < 16; ++dt)
            acc[mf][dt] = (f32x4)(0.0f);

    const int r4 = 8 * wave + 4 * (lane & 1);
    const int d8 = (lane >> 1) * 8;
    float4 ldr[4][2];

    auto LOADT = [&](int n0) {
        #pragma unroll
        for (int rr = 0; rr < 4; ++rr)
            #pragma unroll
            for (int h = 0; h < 2; ++h)
                ldr[rr][h] = *(const float4*)(KV + (size_t)(n0 + r4 + rr) * ND + d8 + 4 * h);
    };

    auto WRITET = [&](int sel) {
        float ps[4];
        unsigned short kb[4][8];
        #pragma unroll
        for (int rr = 0; rr < 4; ++rr) {
            const float4 a = ldr[rr][0], c = ldr[rr][1];
            ps[rr] = a.x*a.x + a.y*a.y + a.z*a.z + a.w*a.w
                   + c.x*c.x + c.y*c.y + c.z*c.z + c.w*c.w;
            kb[rr][0]=f2bf(a.x); kb[rr][1]=f2bf(a.y); kb[rr][2]=f2bf(a.z); kb[rr][3]=f2bf(a.w);
            kb[rr][4]=f2bf(c.x); kb[rr][5]=f2bf(c.y); kb[rr][6]=f2bf(c.z); kb[rr][7]=f2bf(c.w);
            const int r = r4 + rr;
            *(s16x8*)&Klds[sel][r * 256 + (d8 ^ ((r & 7) << 3))] = *(const s16x8*)kb[rr];
        }
        #pragma unroll
        for (int dd = 0; dd < 8; ++dd) {
            const int d = d8 + dd;
            *(ushort4*)&VTlds[sel][d * 32 + (r4 ^ (((d >> 3) & 3) << 3))] =
                make_ushort4(kb[0][dd], kb[1][dd], kb[2][dd], kb[3][dd]);
        }
        #pragma unroll
        for (int rr = 0; rr < 4; ++rr) {
            ps[rr] += __shfl_xor(ps[rr], 2);
            ps[rr] += __shfl_xor(ps[rr], 4);
            ps[rr] += __shfl_xor(ps[rr], 8);
            ps[rr] += __shfl_xor(ps[rr], 16);
            ps[rr] += __shfl_xor(ps[rr], 32);
        }
        if (lane < 2) {
            #pragma unroll
            for (int rr = 0; rr < 4; ++rr)
                KextLds[sel][8 * wave + 4 * lane + rr] =
                    (unsigned int)f2bf(ps[rr]) | 0x3F800000u;
        }
    };

    LOADT(0);
    WRITET(0);

    #pragma unroll 2
    for (int t = 0; t < NITER; ++t) {
        __syncthreads();
        const int sel = t & 1;
        if (t + 1 < NITER) LOADT((t + 1) * 32);

        unsigned int p0 = 0u, p1 = 0u;
        if (lq == 0) { p0 = KextLds[sel][lr]; p1 = KextLds[sel][16 + lr]; }
        union { unsigned int u[4]; s16x8 v; } keu0, keu1;
        keu0.u[0] = p0; keu0.u[1] = 0; keu0.u[2] = 0; keu0.u[3] = 0;
        keu1.u[0] = p1; keu1.u[1] = 0; keu1.u[2] = 0; keu1.u[3] = 0;

        f32x4 sacc[2][2];
        sacc[0][0] = (f32x4)(0.0f); sacc[0][1] = (f32x4)(0.0f);
        sacc[1][0] = (f32x4)(0.0f); sacc[1][1] = (f32x4)(0.0f);
        __builtin_amdgcn_s_setprio(1);
        #pragma unroll
        for (int kk = 0; kk < 8; ++kk) {
            const int cs = (kk * 32 + lq * 8) ^ ((lr & 7) << 3);
            const s16x8 kf0 = *(const s16x8*)&Klds[sel][lr * 256 + cs];
            const s16x8 kf1 = *(const s16x8*)&Klds[sel][(16 + lr) * 256 + cs];
            sacc[0][0] = __builtin_amdgcn_mfma_f32_16x16x32_bf16(kf0, qf[0][kk], sacc[0][0], 0, 0, 0);
            sacc[0][1] = __builtin_amdgcn_mfma_f32_16x16x32_bf16(kf0, qf[1][kk], sacc[0][1], 0, 0, 0);
            sacc[1][0] = __builtin_amdgcn_mfma_f32_16x16x32_bf16(kf1, qf[0][kk], sacc[1][0], 0, 0, 0);
            sacc[1][1] = __builtin_amdgcn_mfma_f32_16x16x32_bf16(kf1, qf[1][kk], sacc[1][1], 0, 0, 0);
        }
        sacc[0][0] = __builtin_amdgcn_mfma_f32_16x16x32_bf16(keu0.v, qe[0], sacc[0][0], 0, 0, 0);
        sacc[0][1] = __builtin_amdgcn_mfma_f32_16x16x32_bf16(keu0.v, qe[1], sacc[0][1], 0, 0, 0);
        sacc[1][0] = __builtin_amdgcn_mfma_f32_16x16x32_bf16(keu1.v, qe[0], sacc[1][0], 0, 0, 0);
        sacc[1][1] = __builtin_amdgcn_mfma_f32_16x16x32_bf16(keu1.v, qe[1], sacc[1][1], 0, 0, 0);
        __builtin_amdgcn_s_setprio(0);

        #pragma unroll
        for (int ns = 0; ns < 2; ++ns) {
            #pragma unroll
            for (int mf = 0; mf < 2; ++mf) {
                unsigned short w4[4];
                #pragma unroll
                for (int j = 0; j < 4; ++j) {
                    float d2 = sacc[ns][mf][j];
                    d2 = d2 > 0.0f ? d2 : 0.0f;
                    w4[j] = f2bf(__builtin_amdgcn_rcpf(1.0f + __builtin_amdgcn_sqrtf(d2)));
                }
                const int row = mf * 16 + lr;
                const int col = (ns * 16 + lq * 4) ^ ((row & 3) << 3);
                *(ushort4*)&Wlds[wave * 1024 + row * 32 + col] =
                    make_ushort4(w4[0], w4[1], w4[2], w4[3]);
            }
        }

        s16x8 wfr[2];
        #pragma unroll
        for (int mf = 0; mf < 2; ++mf)
            wfr[mf] = *(const s16x8*)&Wlds[wave * 1024 + (mf * 16 + lr) * 32 +
                                           ((lq * 8) ^ ((lr & 3) << 3))];
        __builtin_amdgcn_s_setprio(1);
        #pragma unroll
        for (int dt = 0; dt < 16; ++dt) {
            const int vr = dt * 16 + lr;
            const s16x8 vf = *(const s16x8*)&VTlds[sel][vr * 32 +
                                                        ((lq * 8) ^ (((vr >> 3) & 3) << 3))];
            acc[0][dt] = __builtin_amdgcn_mfma_f32_16x16x32_bf16(vf, wfr[0], acc[0][dt], 0, 0, 0);
            acc[1][dt] = __builtin_amdgcn_mfma_f32_16x16x32_bf16(vf, wfr[1], acc[1][dt], 0, 0, 0);
        }
        __builtin_amdgcn_s_setprio(0);

        if (t + 1 < NITER) WRITET(sel ^ 1);
    }

    if (isB) {
        if (part) {
            float* p = part + (size_t)idx * 32768;
            #pragma unroll
            for (int mf = 0; mf < 2; ++mf) {
                const size_t rowbase = (size_t)(wave * 32 + mf * 16 + lr) * ND;
                #pragma unroll
                for (int dt = 0; dt < 16; ++dt) {
                    const f32x4 v = acc[mf][dt];
                    *(float4*)(p + rowbase + dt * 16 + lq * 4) = make_float4(v[0], v[1], v[2], v[3]);
                }
            }
        } else {
            #pragma unroll
            for (int mf = 0; mf < 2; ++mf) {
                float* rowp = out + outbase + (size_t)(wave * 32 + mf * 16 + lr) * ND;
                #pragma unroll
                for (int dt = 0; dt < 16; ++dt)
                    #pragma unroll
                    for (int j = 0; j < 4; ++j)
                        atomicAdd(rowp + dt * 16 + lq * 4 + j, acc[mf][dt][j]);
            }
        }
    } else {
        #pragma unroll
        for (int mf = 0; mf < 2; ++mf) {
            const size_t rowbase = outbase + (size_t)(wave * 32 + mf * 16 + lr) * ND;
            #pragma unroll
            for (int dt = 0; dt < 16; ++dt) {
                const f32x4 v = acc[mf][dt];
                *(float4*)(out + rowbase + dt * 16 + lq * 4) = make_float4(v[0], v[1], v[2], v[3]);
            }
        }
    }
}

extern "C" void kernel_launch(void* const* d_in, const int* in_sizes, int n_in,
                              void* d_out, int out_size, void* d_ws, size_t ws_size,
                              hipStream_t stream) {
    const float* ctx = (const float*)d_in[0];   // [32, 2048, 256] fp32
    const float* tgt = (const float*)d_in[1];   // [32, 512, 256] fp32
    float* out = (float*)d_out;                 // [32, 2560, 256] fp32

    const size_t OFF_NORMS = 0;
    const size_t OFF_CTXB  = 327680;
    const size_t OFF_TGTB  = OFF_CTXB + 33554432;
    const size_t OFF_CTXT  = OFF_TGTB + 8388608;
    const size_t OFF_TGTT  = OFF_CTXT + 33554432;
    const size_t OFF_W     = OFF_TGTT + 8388608;
    const size_t OFF_WT    = OFF_W + 67108864;
    const size_t NEED_NEW  = OFF_WT + 67108864;   // 218,431,488 (proven available)

    char* ws = (char*)d_ws;
    if (ws_size >= NEED_NEW) {
        float* norms = (float*)(ws + OFF_NORMS);
        unsigned short* ctxb = (unsigned short*)(ws + OFF_CTXB);
        unsigned short* tgtb = (unsigned short*)(ws + OFF_TGTB);
        unsigned short* ctxT = (unsigned short*)(ws + OFF_CTXT);
        unsigned short* tgtT = (unsigned short*)(ws + OFF_TGTT);
        unsigned short* Wg   = (unsigned short*)(ws + OFF_W);
        unsigned short* WTg  = (unsigned short*)(ws + OFF_WT);

        prep_kernel<<<20480, 256, 0, stream>>>(ctx, tgt, norms, ctxb, tgtb);
        transpose_bf<<<5120, 256, 0, stream>>>(ctxb, tgtb, ctxT, tgtT);
        k1_weights<<<2048, 256, 0, stream>>>(ctxb, tgtb, norms, Wg, WTg);
        k2_gemm<<<512, 256, 0, stream>>>(tgtT, Wg, out);
        k3v4<<<1024, 256, 0, stream>>>(ctxT, WTg, out);
    } else {
        const size_t need = (size_t)512 * 128 * 256 * 4;
        if (ws_size >= need) {
            float* part = (float*)d_ws;
            fused_dist_attn<<<1024, 256, 0, stream>>>(ctx, tgt, out, part);
            reduce_g2t<<<1024, 256, 0, stream>>>(part, out);
        } else {
            zero_g2t<<<1024, 256, 0, stream>>>(out);
            fused_dist_attn<<<1024, 256, 0, stream>>>(ctx, tgt, out, nullptr);
        }
    }
}

// Round 11
// 183.972 us; speedup vs baseline: 1.4187x; 1.4187x over previous
//
#include <hip/hip_runtime.h>

typedef float f32x4 __attribute__((ext_vector_type(4)));
typedef short s16x8 __attribute__((ext_vector_type(8)));

#define NB_    32
#define NLC    2048
#define NLT    512
#define ND     256
#define NCHUNK 512
#define NITER  (NCHUNK / 32)

__device__ __forceinline__ unsigned short f2bf(float f) {
    union { float f; unsigned int u; } v; v.f = f;
    unsigned int r = v.u + 0x7FFFu + ((v.u >> 16) & 1u);   // RNE to bf16
    return (unsigned short)(r >> 16);
}

__device__ __forceinline__ s16x8 cvt8(float4 a, float4 c, float s) {
    s16x8 f;
    f[0]=(short)f2bf(s*a.x); f[1]=(short)f2bf(s*a.y); f[2]=(short)f2bf(s*a.z); f[3]=(short)f2bf(s*a.w);
    f[4]=(short)f2bf(s*c.x); f[5]=(short)f2bf(s*c.y); f[6]=(short)f2bf(s*c.z); f[7]=(short)f2bf(s*c.w);
    return f;
}

// async global->LDS, 16B per lane (dest = wave-uniform base + lane*16)
__device__ __forceinline__ void glds16(const void* g, void* l) {
    __builtin_amdgcn_global_load_lds(
        (const __attribute__((address_space(1))) unsigned int*)g,
        (__attribute__((address_space(3))) unsigned int*)l, 16, 0, 0);
}

// ---------------------------------------------------------------------------
// Prep: bf16 copies of ctx/tgt + row squared-norms. One wave per row.
// ---------------------------------------------------------------------------
__global__ __launch_bounds__(256) void prep_kernel(
    const float* __restrict__ ctx, const float* __restrict__ tgt,
    float* __restrict__ norms,
    unsigned short* __restrict__ ctxb, unsigned short* __restrict__ tgtb)
{
    const int wave = threadIdx.x >> 6;
    const int lane = threadIdx.x & 63;
    const int rid = blockIdx.x * 4 + wave;
    const float* row;
    unsigned short* drow;
    if (rid < NB_ * NLC) { row = ctx + (size_t)rid * ND; drow = ctxb + (size_t)rid * ND; }
    else { row = tgt + (size_t)(rid - NB_ * NLC) * ND; drow = tgtb + (size_t)(rid - NB_ * NLC) * ND; }
    const float4 v = *(const float4*)(row + lane * 4);
    *(ushort4*)(drow + lane * 4) = make_ushort4(f2bf(v.x), f2bf(v.y), f2bf(v.z), f2bf(v.w));
    float s = v.x * v.x + v.y * v.y + v.z * v.z + v.w * v.w;
    #pragma unroll
    for (int off = 32; off >= 1; off >>= 1) s += __shfl_xor(s, off);
    if (lane == 0) norms[rid] = s;
}

// ---------------------------------------------------------------------------
// Transpose to PACKED panel layouts:
//   ctxTp[b][cs=c/64][256 d][64]   tgtTp[b][ts=t/64][256 d][64]
// 64x64 tiles via LDS. grid: 4096 ctx tiles + 1024 tgt tiles.
// ---------------------------------------------------------------------------
__global__ __launch_bounds__(256) void transpose_bf(
    const unsigned short* __restrict__ ctxb, const unsigned short* __restrict__ tgtb,
    unsigned short* __restrict__ ctxTp, unsigned short* __restrict__ tgtTp)
{
    __shared__ unsigned short tile[64][72];
    const int id = blockIdx.x;
    const unsigned short* in;
    unsigned short* outp;
    const int t = threadIdx.x;
    if (id < 4096) {
        const int b = id >> 7, r = id & 127, lt = r >> 2, dt = r & 3;
        in   = ctxb + ((size_t)b * NLC + lt * 64) * ND + dt * 64;
        outp = ctxTp + (((size_t)b * 32 + lt) * 256 + dt * 64) * 64;
    } else {
        const int id2 = id - 4096;
        const int b = id2 >> 5, r = id2 & 31, lt = r >> 2, dt = r & 3;
        in   = tgtb + ((size_t)b * NLT + lt * 64) * ND + dt * 64;
        outp = tgtTp + (((size_t)b * 8 + lt) * 256 + dt * 64) * 64;
    }
    const int r0 = t >> 2, c0 = t & 3;
    const s16x8 v0 = *(const s16x8*)&in[(size_t)r0 * ND + c0 * 8];
    const s16x8 v1 = *(const s16x8*)&in[(size_t)r0 * ND + (c0 + 4) * 8];
    *(s16x8*)&tile[r0][c0 * 8] = v0;
    *(s16x8*)&tile[r0][(c0 + 4) * 8] = v1;
    __syncthreads();
    unsigned short buf[16];
    #pragma unroll
    for (int i = 0; i < 16; ++i) buf[i] = tile[(t & 3) * 16 + i][t >> 2];
    // output row (within panel) = t>>2, cols (t&3)*16 .. +15 of the 64-panel
    unsigned short* op = outp + (size_t)(t >> 2) * 64 + (t & 3) * 16;
    *(s16x8*)&op[0] = *(const s16x8*)&buf[0];
    *(s16x8*)&op[8] = *(const s16x8*)&buf[8];
}

// ---------------------------------------------------------------------------
// K1: S = ctx.tgt^T -> weights, written in PACKED panel layouts:
//   Wp [b][ts=t/64][c 2048][64]   (k2's B)
//   WTp[b][cs=c/64][t  512][64]   (k3's B)
// (R10-proven.)
// ---------------------------------------------------------------------------
__global__ __launch_bounds__(256, 2) void k1_weights(
    const unsigned short* __restrict__ ctxb, const unsigned short* __restrict__ tgtb,
    const float* __restrict__ norms,
    unsigned short* __restrict__ Wg, unsigned short* __restrict__ WTg)
{
    __shared__ __align__(16) unsigned short Alds[2][128 * 64];   // [c][k] swz; reused as WTs
    __shared__ __align__(16) unsigned short Blds[2][128 * 64];   // [t][k] swz
    __shared__ __align__(16) unsigned short relay[4][16 * 128];

    const int phys = blockIdx.x;
    const int L = (phys & 7) * 256 + (phys >> 3);   // grid 2048, bijective
    const int b = L >> 6;
    const int r = L & 63;
    const int cb = r >> 2, tb = r & 3;

    const int tid = threadIdx.x, wave = tid >> 6, lane = tid & 63;
    const int lr = lane & 15, lq = lane >> 4;
    const int cw = cb * 128 + wave * 32;

    const unsigned short* Actx = ctxb + ((size_t)b * NLC + cb * 128) * ND;
    const unsigned short* Btgt = tgtb + ((size_t)b * NLT + tb * 128) * ND;

    auto STAGE = [&](int buf, int ks) {
        #pragma unroll
        for (int i = 0; i < 4; ++i) {
            const int q = wave * 4 + i;
            const int rloc = q * 8 + (lane >> 3);
            const int gcol = (lane & 7) ^ (rloc & 7);
            glds16(Actx + (size_t)rloc * ND + ks * 64 + gcol * 8, &Alds[buf][q * 512]);
            glds16(Btgt + (size_t)rloc * ND + ks * 64 + gcol * 8, &Blds[buf][q * 512]);
        }
    };

    f32x4 acc[2][8];
    #pragma unroll
    for (int mf = 0; mf < 2; ++mf)
        #pragma unroll
        for (int nf = 0; nf < 8; ++nf) acc[mf][nf] = (f32x4)(0.0f);

    STAGE(0, 0);
    int buf = 0;
    for (int ks = 0; ks < 4; ++ks) {
        __syncthreads();
        if (ks < 3) STAGE(buf ^ 1, ks + 1);
        #pragma unroll
        for (int kk = 0; kk < 2; ++kk) {
            s16x8 af[2];
            #pragma unroll
            for (int mf = 0; mf < 2; ++mf) {
                const int row = wave * 32 + mf * 16 + lr;
                af[mf] = *(const s16x8*)&Alds[buf][row * 64 + (((kk * 4 + lq) ^ (row & 7)) * 8)];
            }
            #pragma unroll
            for (int nf = 0; nf < 8; ++nf) {
                const int row = nf * 16 + lr;
                const s16x8 bf = *(const s16x8*)&Blds[buf][row * 64 + (((kk * 4 + lq) ^ (row & 7)) * 8)];
                acc[0][nf] = __builtin_amdgcn_mfma_f32_16x16x32_bf16(af[0], bf, acc[0][nf], 0, 0, 0);
                acc[1][nf] = __builtin_amdgcn_mfma_f32_16x16x32_bf16(af[1], bf, acc[1][nf], 0, 0, 0);
            }
        }
        buf ^= 1;
    }

    float c2[2][4], t2[8];
    #pragma unroll
    for (int mf = 0; mf < 2; ++mf)
        #pragma unroll
        for (int j = 0; j < 4; ++j)
            c2[mf][j] = norms[b * NLC + cw + mf * 16 + lq * 4 + j];
    #pragma unroll
    for (int nf = 0; nf < 8; ++nf)
        t2[nf] = norms[NB_ * NLC + b * NLT + tb * 128 + nf * 16 + lr];

    __syncthreads();   // all waves done with Alds/Blds; Alds becomes WTs
    unsigned short* WTs = (unsigned short*)Alds;   // [128 t][128 c], c ^= (t&15)<<3

    #pragma unroll
    for (int mf = 0; mf < 2; ++mf) {
        #pragma unroll
        for (int nf = 0; nf < 8; ++nf) {
            unsigned short w4[4];
            #pragma unroll
            for (int j = 0; j < 4; ++j) {
                float d2 = c2[mf][j] + t2[nf] - 2.0f * acc[mf][nf][j];
                d2 = d2 > 0.0f ? d2 : 0.0f;
                w4[j] = f2bf(__builtin_amdgcn_rcpf(1.0f + __builtin_amdgcn_sqrtf(d2)));
                const int row = lq * 4 + j;
                relay[wave][row * 128 + ((nf * 16 + lr) ^ ((row & 7) << 3))] = w4[j];
            }
            const int t = nf * 16 + lr;
            const int c4 = (wave * 32 + mf * 16 + lq * 4) ^ ((t & 15) << 3);
            *(ushort4*)&WTs[t * 128 + c4] = make_ushort4(w4[0], w4[1], w4[2], w4[3]);
        }
        __syncthreads();
        // Wp packed write
        {
            const int rrow = lane >> 2;
            const int ts   = (lane >> 1) & 1;
            const int half = lane & 1;
            const size_t wbase =
                (((size_t)b * 8 + tb * 2 + ts) * NLC + cb * 128 + wave * 32 + mf * 16 + rrow) * 64
                + half * 32;
            #pragma unroll
            for (int e = 0; e < 4; ++e) {
                const int tcol = ts * 64 + half * 32 + e * 8;
                const s16x8 v = *(const s16x8*)&relay[wave][rrow * 128 + (tcol ^ ((rrow & 7) << 3))];
                *(s16x8*)&Wg[wbase + e * 8] = v;
            }
        }
        __syncthreads();
    }

    // WTp packed write: 128B contiguous/thread
    {
        const int trow = tid >> 1;
        const int seg  = tid & 1;
        const size_t wtbase =
            (((size_t)b * 32 + cb * 2 + seg) * NLT + tb * 128 + trow) * 64;
        #pragma unroll
        for (int e = 0; e < 8; ++e) {
            const int c8 = (seg * 64 + e * 8) ^ ((trow & 15) << 3);
            *(s16x8*)&WTg[wtbase + e * 8] = *(const s16x8*)&WTs[trow * 128 + c8];
        }
    }
}

// ---------------------------------------------------------------------------
// K2: g2c^T GEMM, tile 128 c x 256 d, BK=64, K=512 (=t).
// A = tgtTp packed panels via global_load_lds; B = Wp packed panels.
// ---------------------------------------------------------------------------
__global__ __launch_bounds__(256, 2) void k2_gemm(
    const unsigned short* __restrict__ Atp, const unsigned short* __restrict__ Wp,
    float* __restrict__ outp)
{
    __shared__ __align__(16) unsigned short Slds[2][256 * 64];   // [d][k] swz

    const int phys = blockIdx.x;
    const int L = (phys & 7) * 64 + (phys >> 3);   // grid 512, bijective
    const int b = L >> 4, cb = L & 15;
    float* outB = outp + ((size_t)b * (NLC + NLT) + cb * 128) * ND;

    const int tid = threadIdx.x, wave = tid >> 6, lane = tid & 63;
    const int lr = lane & 15, lq = lane >> 4;

    const int srow = tid >> 3;
    const int schunk = tid & 7;

    auto STAGE = [&](int buf, int ks) {
        #pragma unroll
        for (int i = 0; i < 8; ++i) {
            const int row = i * 32 + srow;
            const int gcol = schunk ^ (row & 7);
            glds16(Atp + (((size_t)b * 8 + ks) * 256 + row) * 64 + gcol * 8,
                   &Slds[buf][(i * 32 + wave * 8) * 64]);
        }
    };

    f32x4 acc[16][2];
    #pragma unroll
    for (int mf = 0; mf < 16; ++mf) { acc[mf][0] = (f32x4)(0.0f); acc[mf][1] = (f32x4)(0.0f); }

    STAGE(0, 0);
    for (int ks = 0; ks < 8; ++ks) {
        __syncthreads();
        const int buf = ks & 1;
        if (ks < 7) STAGE(buf ^ 1, ks + 1);

        s16x8 bfr[2][2];
        #pragma unroll
        for (int j = 0; j < 2; ++j)
            #pragma unroll
            for (int kk = 0; kk < 2; ++kk)
                bfr[j][kk] = *(const s16x8*)&Wp[
                    (((size_t)b * 8 + ks) * NLC + cb * 128 + wave * 32 + j * 16 + lr) * 64
                    + kk * 32 + lq * 8];

        __builtin_amdgcn_s_setprio(1);
        #pragma unroll
        for (int kk = 0; kk < 2; ++kk) {
            #pragma unroll
            for (int mf = 0; mf < 16; ++mf) {
                const int row = mf * 16 + lr;
                const s16x8 af = *(const s16x8*)&Slds[buf][row * 64 +
                                                           (((kk * 4 + lq) ^ (row & 7)) * 8)];
                acc[mf][0] = __builtin_amdgcn_mfma_f32_16x16x32_bf16(af, bfr[0][kk], acc[mf][0], 0, 0, 0);
                acc[mf][1] = __builtin_amdgcn_mfma_f32_16x16x32_bf16(af, bfr[1][kk], acc[mf][1], 0, 0, 0);
            }
        }
        __builtin_amdgcn_s_setprio(0);
    }

    #pragma unroll
    for (int j = 0; j < 2; ++j) {
        const int col = wave * 32 + j * 16 + lr;
        float* rp = outB + (size_t)col * ND;
        #pragma unroll
        for (int mf = 0; mf < 16; ++mf) {
            const f32x4 v = acc[mf][j];
            *(float4*)(rp + mf * 16 + lq * 4) = make_float4(v[0], v[1], v[2], v[3]);
        }
    }
}

// ---------------------------------------------------------------------------
// K3V5: g2t full-K, BOTH operands LDS-staged (each global byte read once per
// block). Grid 256 = (b, tb of 128t, dh of 128d); block 512 thr / 8 waves
// (2d x 4t). K = 2048 (=c), 32 k-steps of 64. LDS 64KB dbuf.
// ---------------------------------------------------------------------------
__global__ __launch_bounds__(512, 2) void k3v5(
    const unsigned short* __restrict__ ctxTp, const unsigned short* __restrict__ WTp,
    float* __restrict__ out)
{
    __shared__ __align__(16) unsigned short Alds[2][128 * 64];   // [d][k] swz
    __shared__ __align__(16) unsigned short Blds[2][128 * 64];   // [t][k] swz

    const int phys = blockIdx.x;
    const int L = (phys & 7) * 32 + (phys >> 3);   // grid 256, bijective
    const int b = L >> 3, r = L & 7;
    const int tb = r >> 1, dh = r & 1;

    const int tid = threadIdx.x, wave = tid >> 6, lane = tid & 63;
    const int lr = lane & 15, lq = lane >> 4;
    const int wd = wave >> 2, wt = wave & 3;   // 2 d-halves x 4 t-quarters

    auto STAGE = [&](int buf, int ks) {
        #pragma unroll
        for (int i = 0; i < 2; ++i) {
            const int q = wave * 2 + i;                 // 0..15
            const int rloc = q * 8 + (lane >> 3);       // 0..127
            const int gcol = (lane & 7) ^ (rloc & 7);
            glds16(ctxTp + (((size_t)b * 32 + ks) * 256 + dh * 128 + rloc) * 64 + gcol * 8,
                   &Alds[buf][q * 512]);
            glds16(WTp + (((size_t)b * 32 + ks) * NLT + tb * 128 + rloc) * 64 + gcol * 8,
                   &Blds[buf][q * 512]);
        }
    };

    f32x4 acc[4][2];   // [mf d-frag][nf t-frag]
    #pragma unroll
    for (int mf = 0; mf < 4; ++mf) { acc[mf][0] = (f32x4)(0.0f); acc[mf][1] = (f32x4)(0.0f); }

    STAGE(0, 0);
    for (int ks = 0; ks < 32; ++ks) {
        __syncthreads();
        const int buf = ks & 1;
        if (ks < 31) STAGE(buf ^ 1, ks + 1);

        __builtin_amdgcn_s_setprio(1);
        #pragma unroll
        for (int kk = 0; kk < 2; ++kk) {
            s16x8 bfr[2];
            #pragma unroll
            for (int nf = 0; nf < 2; ++nf) {
                const int row = wt * 32 + nf * 16 + lr;
                bfr[nf] = *(const s16x8*)&Blds[buf][row * 64 + (((kk * 4 + lq) ^ (row & 7)) * 8)];
            }
            #pragma unroll
            for (int mf = 0; mf < 4; ++mf) {
                const int row = wd * 64 + mf * 16 + lr;
                const s16x8 af = *(const s16x8*)&Alds[buf][row * 64 +
                                                           (((kk * 4 + lq) ^ (row & 7)) * 8)];
                acc[mf][0] = __builtin_amdgcn_mfma_f32_16x16x32_bf16(af, bfr[0], acc[mf][0], 0, 0, 0);
                acc[mf][1] = __builtin_amdgcn_mfma_f32_16x16x32_bf16(af, bfr[1], acc[mf][1], 0, 0, 0);
            }
        }
        __builtin_amdgcn_s_setprio(0);
    }

    // epilogue: out[t][d], d = dh*128 + wd*64 + mf*16 + lq*4+j contiguous
    #pragma unroll
    for (int nf = 0; nf < 2; ++nf) {
        const int t = tb * 128 + wt * 32 + nf * 16 + lr;
        float* rp = out + ((size_t)b * (NLC + NLT) + NLC + t) * ND + dh * 128 + wd * 64;
        #pragma unroll
        for (int mf = 0; mf < 4; ++mf) {
            const f32x4 v = acc[mf][nf];
            *(float4*)(rp + mf * 16 + lq * 4) = make_float4(v[0], v[1], v[2], v[3]);
        }
    }
}

// ===========================================================================
// R4 fused fallback (proven-correct) for small workspaces.
// ===========================================================================
__global__ __launch_bounds__(256) void zero_g2t(float* __restrict__ out) {
    const int g = blockIdx.x * 256 + threadIdx.x;
    #pragma unroll
    for (int k = 0; k < 4; ++k) {
        const int i = g + k * 262144;
        const int bb = i >> 15;
        const int off = i & 32767;
        *(float4*)(out + ((size_t)bb * (NLC + NLT) + NLC) * ND + (size_t)off * 4) =
            make_float4(0.f, 0.f, 0.f, 0.f);
    }
}

__global__ __launch_bounds__(256) void reduce_g2t(const float* __restrict__ part,
                                                  float* __restrict__ out) {
    const int g = blockIdx.x * 256 + threadIdx.x;
    #pragma unroll
    for (int k = 0; k < 4; ++k) {
        const int i = g + k * 262144;
        const int b = i >> 15;
        const int rem = i & 32767;
        const int row = rem >> 6;
        const int d4 = (rem & 63) * 4;
        const int mb = row >> 7, rr = row & 127;
        const size_t base = ((size_t)(b * 16 + mb * 4) * 32768) + (size_t)rr * 256 + d4;
        float4 s0 = *(const float4*)(part + base);
        float4 s1 = *(const float4*)(part + base + 32768);
        float4 s2 = *(const float4*)(part + base + 65536);
        float4 s3 = *(const float4*)(part + base + 98304);
        *(float4*)(out + ((size_t)b * (NLC + NLT) + NLC + row) * ND + d4) =
            make_float4(s0.x + s1.x + s2.x + s3.x, s0.y + s1.y + s2.y + s3.y,
                        s0.z + s1.z + s2.z + s3.z, s0.w + s1.w + s2.w + s3.w);
    }
}

__global__ __launch_bounds__(256, 2) void fused_dist_attn(
    const float* __restrict__ ctx, const float* __restrict__ tgt,
    float* __restrict__ out, float* __restrict__ part)
{
    __shared__ __align__(16) unsigned short Klds[2][32 * 256];
    __shared__ __align__(16) unsigned short VTlds[2][256 * 32];
    __shared__ __align__(16) unsigned short Wlds[4 * 32 * 32];
    __shared__ unsigned int KextLds[2][32];

    const int phys = blockIdx.x;
    const int L = (phys & 7) * 128 + (phys >> 3);
    const int isB = (L & 1) == 0;
    const int idx = L >> 1;
    const int b = idx >> 4;
    const float *Q, *KV;
    size_t outbase;
    if (isB) {
        const int mb = (idx >> 2) & 3, nc = idx & 3;
        Q = tgt + ((size_t)b * NLT + mb * 128) * ND;
        KV = ctx + ((size_t)b * NLC + nc * NCHUNK) * ND;
        outbase = ((size_t)b * (NLC + NLT) + NLC + mb * 128) * ND;
    } else {
        const int mb = idx & 15;
        Q = ctx + ((size_t)b * NLC + mb * 128) * ND;
        KV = tgt + (size_t)b * NLT * ND;
        outbase = ((size_t)b * (NLC + NLT) + mb * 128) * ND;
    }

    const int tid = threadIdx.x, wave = tid >> 6, lane = tid & 63;
    const int lr = lane & 15, lq = lane >> 4;

    s16x8 qf[2][8];
    s16x8 qe[2];
    #pragma unroll
    for (int mf = 0; mf < 2; ++mf) {
        const float* qrow = Q + (size_t)(wave * 32 + mf * 16 + lr) * ND;
        float q2 = 0.0f;
        #pragma unroll
        for (int kk = 0; kk < 8; ++kk) {
            const float4 a = *(const float4*)(qrow + kk * 32 + lq * 8);
            const float4 c = *(const float4*)(qrow + kk * 32 + lq * 8 + 4);
            q2 += a.x*a.x + a.y*a.y + a.z*a.z + a.w*a.w;
            q2 += c.x*c.x + c.y*c.y + c.z*c.z + c.w*c.w;
            qf[mf][kk] = cvt8(a, c, -2.0f);
        }
        q2 += __shfl_xor(q2, 16);
        q2 += __shfl_xor(q2, 32);
        union { unsigned int u[4]; s16x8 v; } qu;
        qu.u[0] = (lq == 0) ? (0x3F80u | ((unsigned int)f2bf(q2) << 16)) : 0u;
        qu.u[1] = 0u; qu.u[2] = 0u; qu.u[3] = 0u;
        qe[mf] = qu.v;
    }

    f32x4 acc[2][16];
    #pragma unroll
    for (int mf = 0; mf < 2; ++mf)
        #pragma unroll
        for (int dt = 0; dt < 16; ++dt)
            acc[mf][dt] = (f32x4)(0.0f);

    const int r4 = 8 * wave + 4 * (lane & 1);
    const int d8 = (lane >> 1) * 8;
    float4 ldr[4][2];

    auto LOADT = [&](int n0) {
        #pragma unroll
        for (int rr = 0; rr < 4; ++rr)
            #pragma unroll
            for (int h = 0; h < 2; ++h)
                ldr[rr][h] = *(const float4*)(KV + (size_t)(n0 + r4 + rr) * ND + d8 + 4 * h);
    };

    auto WRITET = [&](int sel) {
        float ps[4];
        unsigned short kb[4][8];
        #pragma unroll
        for (int rr = 0; rr < 4; ++rr) {
            const float4 a = ldr[rr][0], c = ldr[rr][1];
            ps[rr] = a.x*a.x + a.y*a.y + a.z*a.z + a.w*a.w
                   + c.x*c.x + c.y*c.y + c.z*c.z + c.w*c.w;
            kb[rr][0]=f2bf(a.x); kb[rr][1]=f2bf(a.y); kb[rr][2]=f2bf(a.z); kb[rr][3]=f2bf(a.w);
            kb[rr][4]=f2bf(c.x); kb[rr][5]=f2bf(c.y); kb[rr][6]=f2bf(c.z); kb[rr][7]=f2bf(c.w);
            const int rx = r4 + rr;
            *(s16x8*)&Klds[sel][rx * 256 + (d8 ^ ((rx & 7) << 3))] = *(const s16x8*)kb[rr];
        }
        #pragma unroll
        for (int dd = 0; dd < 8; ++dd) {
            const int d = d8 + dd;
            *(ushort4*)&VTlds[sel][d * 32 + (r4 ^ (((d >> 3) & 3) << 3))] =
                make_ushort4(kb[0][dd], kb[1][dd], kb[2][dd], kb[3][dd]);
        }
        #pragma unroll
        for (int rr = 0; rr < 4; ++rr) {
            ps[rr] += __shfl_xor(ps[rr], 2);
            ps[rr] += __shfl_xor(ps[rr], 4);
            ps[rr] += __shfl_xor(ps[rr], 8);
            ps[rr] += __shfl_xor(ps[rr], 16);
            ps[rr] += __shfl_xor(ps[rr], 32);
        }
        if (lane < 2) {
            #pragma unroll
            for (int rr = 0; rr < 4; ++rr)
                KextLds[sel][8 * wave + 4 * lane + rr] =
                    (unsigned int)f2bf(ps[rr]) | 0x3F800000u;
        }
    };

    LOADT(0);
    WRITET(0);

    #pragma unroll 2
    for (int t = 0; t < NITER; ++t) {
        __syncthreads();
        const int sel = t & 1;
        if (t + 1 < NITER) LOADT((t + 1) * 32);

        unsigned int p0 = 0u, p1 = 0u;
        if (lq == 0) { p0 = KextLds[sel][lr]; p1 = KextLds[sel][16 + lr]; }
        union { unsigned int u[4]; s16x8 v; } keu0, keu1;
        keu0.u[0] = p0; keu0.u[1] = 0; keu0.u[2] = 0; keu0.u[3] = 0;
        keu1.u[0] = p1; keu1.u[1] = 0; keu1.u[2] = 0; keu1.u[3] = 0;

        f32x4 sacc[2][2];
        sacc[0][0] = (f32x4)(0.0f); sacc[0][1] = (f32x4)(0.0f);
        sacc[1][0] = (f32x4)(0.0f); sacc[1][1] = (f32x4)(0.0f);
        __builtin_amdgcn_s_setprio(1);
        #pragma unroll
        for (int kk = 0; kk < 8; ++kk) {
            const int cs = (kk * 32 + lq * 8) ^ ((lr & 7) << 3);
            const s16x8 kf0 = *(const s16x8*)&Klds[sel][lr * 256 + cs];
            const s16x8 kf1 = *(const s16x8*)&Klds[sel][(16 + lr) * 256 + cs];
            sacc[0][0] = __builtin_amdgcn_mfma_f32_16x16x32_bf16(kf0, qf[0][kk], sacc[0][0], 0, 0, 0);
            sacc[0][1] = __builtin_amdgcn_mfma_f32_16x16x32_bf16(kf0, qf[1][kk], sacc[0][1], 0, 0, 0);
            sacc[1][0] = __builtin_amdgcn_mfma_f32_16x16x32_bf16(kf1, qf[0][kk], sacc[1][0], 0, 0, 0);
            sacc[1][1] = __builtin_amdgcn_mfma_f32_16x16x32_bf16(kf1, qf[1][kk], sacc[1][1], 0, 0, 0);
        }
        sacc[0][0] = __builtin_amdgcn_mfma_f32_16x16x32_bf16(keu0.v, qe[0], sacc[0][0], 0, 0, 0);
        sacc[0][1] = __builtin_amdgcn_mfma_f32_16x16x32_bf16(keu0.v, qe[1], sacc[0][1], 0, 0, 0);
        sacc[1][0] = __builtin_amdgcn_mfma_f32_16x16x32_bf16(keu1.v, qe[0], sacc[1][0], 0, 0, 0);
        sacc[1][1] = __builtin_amdgcn_mfma_f32_16x16x32_bf16(keu1.v, qe[1], sacc[1][1], 0, 0, 0);
        __builtin_amdgcn_s_setprio(0);

        #pragma unroll
        for (int ns = 0; ns < 2; ++ns) {
            #pragma unroll
            for (int mf = 0; mf < 2; ++mf) {
                unsigned short w4[4];
                #pragma unroll
                for (int j = 0; j < 4; ++j) {
                    float d2 = sacc[ns][mf][j];
                    d2 = d2 > 0.0f ? d2 : 0.0f;
                    w4[j] = f2bf(__builtin_amdgcn_rcpf(1.0f + __builtin_amdgcn_sqrtf(d2)));
                }
                const int row = mf * 16 + lr;
                const int col = (ns * 16 + lq * 4) ^ ((row & 3) << 3);
                *(ushort4*)&Wlds[wave * 1024 + row * 32 + col] =
                    make_ushort4(w4[0], w4[1], w4[2], w4[3]);
            }
        }

        s16x8 wfr[2];
        #pragma unroll
        for (int mf = 0; mf < 2; ++mf)
            wfr[mf] = *(const s16x8*)&Wlds[wave * 1024 + (mf * 16 + lr) * 32 +
                                           ((lq * 8) ^ ((lr & 3) << 3))];
        __builtin_amdgcn_s_setprio(1);
        #pragma unroll
        for (int dt = 0; dt < 16; ++dt) {
            const int vr = dt * 16 + lr;
            const s16x8 vf = *(const s16x8*)&VTlds[sel][vr * 32 +
                                                        ((lq * 8) ^ (((vr >> 3) & 3) << 3))];
            acc[0][dt] = __builtin_amdgcn_mfma_f32_16x16x32_bf16(vf, wfr[0], acc[0][dt], 0, 0, 0);
            acc[1][dt] = __builtin_amdgcn_mfma_f32_16x16x32_bf16(vf, wfr[1], acc[1][dt], 0, 0, 0);
        }
        __builtin_amdgcn_s_setprio(0);

        if (t + 1 < NITER) WRITET(sel ^ 1);
    }

    if (isB) {
        if (part) {
            float* p = part + (size_t)idx * 32768;
            #pragma unroll
            for (int mf = 0; mf < 2; ++mf) {
                const size_t rowbase = (size_t)(wave * 32 + mf * 16 + lr) * ND;
                #pragma unroll
                for (int dt = 0; dt < 16; ++dt) {
                    const f32x4 v = acc[mf][dt];
                    *(float4*)(p + rowbase + dt * 16 + lq * 4) = make_float4(v[0], v[1], v[2], v[3]);
                }
            }
        } else {
            #pragma unroll
            for (int mf = 0; mf < 2; ++mf) {
                float* rowp = out + outbase + (size_t)(wave * 32 + mf * 16 + lr) * ND;
                #pragma unroll
                for (int dt = 0; dt < 16; ++dt)
                    #pragma unroll
                    for (int j = 0; j < 4; ++j)
                        atomicAdd(rowp + dt * 16 + lq * 4 + j, acc[mf][dt][j]);
            }
        }
    } else {
        #pragma unroll
        for (int mf = 0; mf < 2; ++mf) {
            const size_t rowbase = outbase + (size_t)(wave * 32 + mf * 16 + lr) * ND;
            #pragma unroll
            for (int dt = 0; dt < 16; ++dt) {
                const f32x4 v = acc[mf][dt];
                *(float4*)(out + rowbase + dt * 16 + lq * 4) = make_float4(v[0], v[1], v[2], v[3]);
            }
        }
    }
}

extern "C" void kernel_launch(void* const* d_in, const int* in_sizes, int n_in,
                              void* d_out, int out_size, void* d_ws, size_t ws_size,
                              hipStream_t stream) {
    const float* ctx = (const float*)d_in[0];   // [32, 2048, 256] fp32
    const float* tgt = (const float*)d_in[1];   // [32, 512, 256] fp32
    float* out = (float*)d_out;                 // [32, 2560, 256] fp32

    const size_t OFF_NORMS = 0;
    const size_t OFF_CTXB  = 327680;
    const size_t OFF_TGTB  = OFF_CTXB + 33554432;
    const size_t OFF_CTXT  = OFF_TGTB + 8388608;
    const size_t OFF_TGTT  = OFF_CTXT + 33554432;
    const size_t OFF_W     = OFF_TGTT + 8388608;
    const size_t OFF_WT    = OFF_W + 67108864;
    const size_t NEED_NEW  = OFF_WT + 67108864;   // 218,431,488 (proven available)

    char* ws = (char*)d_ws;
    if (ws_size >= NEED_NEW) {
        float* norms = (float*)(ws + OFF_NORMS);
        unsigned short* ctxb  = (unsigned short*)(ws + OFF_CTXB);
        unsigned short* tgtb  = (unsigned short*)(ws + OFF_TGTB);
        unsigned short* ctxTp = (unsigned short*)(ws + OFF_CTXT);
        unsigned short* tgtTp = (unsigned short*)(ws + OFF_TGTT);
        unsigned short* Wg    = (unsigned short*)(ws + OFF_W);
        unsigned short* WTg   = (unsigned short*)(ws + OFF_WT);

        prep_kernel<<<20480, 256, 0, stream>>>(ctx, tgt, norms, ctxb, tgtb);
        transpose_bf<<<5120, 256, 0, stream>>>(ctxb, tgtb, ctxTp, tgtTp);
        k1_weights<<<2048, 256, 0, stream>>>(ctxb, tgtb, norms, Wg, WTg);
        k2_gemm<<<512, 256, 0, stream>>>(tgtTp, Wg, out);
        k3v5<<<256, 512, 0, stream>>>(ctxTp, WTg, out);
    } else {
        const size_t need = (size_t)512 * 128 * 256 * 4;
        if (ws_size >= need) {
            float* part = (float*)d_ws;
            fused_dist_attn<<<1024, 256, 0, stream>>>(ctx, tgt, out, part);
            reduce_g2t<<<1024, 256, 0, stream>>>(part, out);
        } else {
            zero_g2t<<<1024, 256, 0, stream>>>(out);
            fused_dist_attn<<<1024, 256, 0, stream>>>(ctx, tgt, out, nullptr);
        }
    }
}